// Round 14
// baseline (131.523 us; speedup 1.0000x reference)
//
#include <hip/hip_runtime.h>
#include <hip/hip_bf16.h>
#include <stdint.h>

typedef __bf16 bf16;
typedef __bf16 bf16x4 __attribute__((ext_vector_type(4)));
typedef __bf16 bf16x8 __attribute__((ext_vector_type(8)));
typedef float  f32x4  __attribute__((ext_vector_type(4)));
typedef float  f32x16 __attribute__((ext_vector_type(16)));

#define MFMA32(A_, B_, C_) __builtin_amdgcn_mfma_f32_32x32x16_bf16((A_), (B_), (C_), 0, 0, 0)

#define QSCALE 0.1803368801111137f  // 0.125 * log2(e), folded into Wq/bq

__device__ __forceinline__ void gload_lds16(const void* g, void* l) {
  __builtin_amdgcn_global_load_lds(
      (const __attribute__((address_space(1))) unsigned int*)g,
      (__attribute__((address_space(3))) unsigned int*)l, 16, 0, 0);
}

__device__ __forceinline__ unsigned pk2(float lo, float hi_) {
  union { bf16 h[2]; unsigned u; } t;
  t.h[0] = (bf16)lo; t.h[1] = (bf16)hi_;
  return t.u;
}

__device__ __forceinline__ float fast_exp2(float x) {
#if __has_builtin(__builtin_amdgcn_exp2f)
  return __builtin_amdgcn_exp2f(x);
#else
  return exp2f(x);
#endif
}

// ---------------------------------------------------------------------------
// prep_ln: blocks 0..773 = weight transposes + bias pack; 774..1797 = LN1.
// ---------------------------------------------------------------------------
__global__ __launch_bounds__(256) void prep_ln(const float* __restrict__ Wq,
                                               const float* __restrict__ Wk,
                                               const float* __restrict__ Wv,
                                               const float* __restrict__ Wo,
                                               const float* __restrict__ W1,
                                               const float* __restrict__ W2,
                                               const float* __restrict__ bq,
                                               const float* __restrict__ bk,
                                               const float* __restrict__ bv,
                                               bf16* __restrict__ wqkvT, bf16* __restrict__ woT,
                                               bf16* __restrict__ w1T, bf16* __restrict__ w2T,
                                               float* __restrict__ bqkv,
                                               const float* __restrict__ x,
                                               const float* __restrict__ ln1s,
                                               const float* __restrict__ ln1b,
                                               bf16* __restrict__ h) {
  const int b = blockIdx.x;
  if (b >= 774) {  // ---- LayerNorm rows ----
    const int w = threadIdx.x >> 6, l = threadIdx.x & 63;
    const int row = (b - 774) * 4 + w;
    const float4* xp = (const float4*)(x + (size_t)row * 512 + l * 8);
    float4 v0 = xp[0], v1 = xp[1];
    float xv[8] = {v0.x, v0.y, v0.z, v0.w, v1.x, v1.y, v1.z, v1.w};
    float s = 0.f, q = 0.f;
#pragma unroll
    for (int j = 0; j < 8; ++j) { s += xv[j]; q += xv[j] * xv[j]; }
#pragma unroll
    for (int m = 1; m < 64; m <<= 1) { s += __shfl_xor(s, m); q += __shfl_xor(q, m); }
    const float mean = s * (1.f / 512.f);
    const float var = q * (1.f / 512.f) - mean * mean;
    const float rstd = rsqrtf(var + 1e-6f);
    const float4* scp = (const float4*)(ln1s + l * 8);
    const float4* bip = (const float4*)(ln1b + l * 8);
    float4 s0 = scp[0], s1 = scp[1], b0 = bip[0], b1 = bip[1];
    float sv[8] = {s0.x, s0.y, s0.z, s0.w, s1.x, s1.y, s1.z, s1.w};
    float bvv[8] = {b0.x, b0.y, b0.z, b0.w, b1.x, b1.y, b1.z, b1.w};
    bf16x8 ov;
#pragma unroll
    for (int j = 0; j < 8; ++j) ov[j] = (bf16)((xv[j] - mean) * rstd * sv[j] + bvv[j]);
    *(bf16x8*)(h + (size_t)row * 512 + l * 8) = ov;
    return;
  }
  if (b >= 768) {  // ---- bias pack ----
    int i = (b - 768) * 256 + threadIdx.x;
    if (i < 1536)
      bqkv[i] = (i < 512) ? bq[i] * QSCALE : (i < 1024 ? bk[i - 512] : bv[i - 1024]);
    return;
  }
  const float* in; bf16* outp; int K, N, t; float sc = 1.f;
  if (b < 64)       { in = Wq; outp = wqkvT;              K = 512;  N = 512;  t = b;       sc = QSCALE; }
  else if (b < 128) { in = Wk; outp = wqkvT + 512 * 512;  K = 512;  N = 512;  t = b - 64;  }
  else if (b < 192) { in = Wv; outp = wqkvT + 1024 * 512; K = 512;  N = 512;  t = b - 128; }
  else if (b < 256) { in = Wo; outp = woT;                K = 512;  N = 512;  t = b - 192; }
  else if (b < 512) { in = W1; outp = w1T;                K = 512;  N = 2048; t = b - 256; }
  else              { in = W2; outp = w2T;                K = 2048; N = 512;  t = b - 512; }
  const int tx = K >> 6;
  const int k0 = (t % tx) * 64, n0 = (t / tx) * 64;
  __shared__ bf16 tile[64][72];
  const int tid = threadIdx.x;
#pragma unroll
  for (int s = 0; s < 16; ++s) {
    int j = tid + s * 256;
    int r = j >> 6, c = j & 63;
    tile[r][c] = (bf16)(in[(size_t)(k0 + r) * N + n0 + c] * sc);
  }
  __syncthreads();
#pragma unroll
  for (int s = 0; s < 16; ++s) {
    int j = tid + s * 256;
    int n = j >> 6, k = j & 63;
    outp[(size_t)(n0 + n) * K + k0 + k] = tile[k][n];
  }
}

// ---------------------------------------------------------------------------
// ln_k: pure LayerNorm, x2 fp32 [4096][512] -> h2 bf16. One wave per row.
// ---------------------------------------------------------------------------
__global__ __launch_bounds__(256) void ln_k(const float* __restrict__ x,
                                            const float* __restrict__ sc,
                                            const float* __restrict__ bi,
                                            bf16* __restrict__ out) {
  const int w = threadIdx.x >> 6, l = threadIdx.x & 63;
  const int row = blockIdx.x * 4 + w;
  const float4* xp = (const float4*)(x + (size_t)row * 512 + l * 8);
  float4 v0 = xp[0], v1 = xp[1];
  float xv[8] = {v0.x, v0.y, v0.z, v0.w, v1.x, v1.y, v1.z, v1.w};
  float s = 0.f, q = 0.f;
#pragma unroll
  for (int j = 0; j < 8; ++j) { s += xv[j]; q += xv[j] * xv[j]; }
#pragma unroll
  for (int m = 1; m < 64; m <<= 1) { s += __shfl_xor(s, m); q += __shfl_xor(q, m); }
  const float mean = s * (1.f / 512.f);
  const float var = q * (1.f / 512.f) - mean * mean;
  const float rstd = rsqrtf(var + 1e-6f);
  const float4* scp = (const float4*)(sc + l * 8);
  const float4* bip = (const float4*)(bi + l * 8);
  float4 s0 = scp[0], s1 = scp[1], b0 = bip[0], b1 = bip[1];
  float sv[8] = {s0.x, s0.y, s0.z, s0.w, s1.x, s1.y, s1.z, s1.w};
  float bvv[8] = {b0.x, b0.y, b0.z, b0.w, b1.x, b1.y, b1.z, b1.w};
  bf16x8 ov;
#pragma unroll
  for (int j = 0; j < 8; ++j) ov[j] = (bf16)((xv[j] - mean) * rstd * sv[j] + bvv[j]);
  *(bf16x8*)(out + (size_t)row * 512 + l * 8) = ov;
}

// ---------------------------------------------------------------------------
// GEMM_N64 (for N=512 outputs): 128x64 tile, 4 waves (2Mx2N, 64x32/wave,
// 2 acc), BK=32, 3-buffer counted-vmcnt pipeline, setprio around compute.
// EPI 1: +bias+res(f32)->f32
// ---------------------------------------------------------------------------
template <int EPI>
__global__ __launch_bounds__(256, 4) void gemm_n64(const bf16* __restrict__ A,
                                                   const bf16* __restrict__ Bt,
                                                   const float* __restrict__ bias,
                                                   const float* __restrict__ res,
                                                   void* __restrict__ outp,
                                                   int M, int N, int K) {
  __shared__ __align__(16) char smem[36864];   // 3 x (8192 A + 4096 B)
  const int tid = threadIdx.x, l = tid & 63, w = tid >> 6;
  const int wm = w >> 1, wn = w & 1;
  const int hi = l >> 5, l5 = l & 31;
  const int m0 = blockIdx.x * 128, n0 = blockIdx.y * 64;
  const int swl = l5 & 7;

  const int sr = tid >> 3, sp = tid & 7;
  const int slc = sp ^ (sr & 7);
  const int shalf = slc >> 2, skc = slc & 3;
  const bf16* ag = A + (size_t)(m0 + shalf * 64 + sr) * K + skc * 8;
  const size_t r32 = (size_t)32 * K;
  const int brow = tid >> 3;
  const int blc = sp ^ (brow & 7);
  const bf16* bg = Bt + (size_t)(n0 + (blc >> 2) * 32 + brow) * K + (blc & 3) * 8;

#define GSN(B_)                                                          \
  do {                                                                   \
    char* ab_ = smem + (B_) * 12288;                                     \
    gload_lds16(ag,       ab_ + w * 1024);                               \
    gload_lds16(ag + r32, ab_ + 4096 + w * 1024);                        \
    gload_lds16(bg,       ab_ + 8192 + w * 1024);                        \
    ag += 32; bg += 32;                                                  \
  } while (0)

  f32x16 acc0 = {}, acc1 = {};
  const int kiters = K >> 5;
  GSN(0);
  GSN(1);
  asm volatile("s_waitcnt vmcnt(3)" ::: "memory");
  __builtin_amdgcn_s_barrier();
  for (int kt = 0; kt < kiters; ++kt) {
    if (kt + 2 < kiters) GSN((kt + 2) % 3);
    const char* ab = smem + (kt % 3) * 12288;
    const char* bb = ab + 8192;
    __builtin_amdgcn_s_setprio(1);
#pragma unroll
    for (int kk = 0; kk < 2; ++kk) {
      bf16x8 af0 = *(const bf16x8*)(ab + (l5)*128      + ((wm * 4 + kk * 2 + hi) ^ swl) * 16);
      bf16x8 af1 = *(const bf16x8*)(ab + (32 + l5)*128 + ((wm * 4 + kk * 2 + hi) ^ swl) * 16);
      bf16x8 bf_ = *(const bf16x8*)(bb + (l5)*128      + ((wn * 4 + kk * 2 + hi) ^ swl) * 16);
      acc0 = MFMA32(bf_, af0, acc0);
      acc1 = MFMA32(bf_, af1, acc1);
    }
    __builtin_amdgcn_s_setprio(0);
    if (kt + 1 < kiters) {
      if (kt + 2 < kiters) asm volatile("s_waitcnt vmcnt(3)" ::: "memory");
      else                 asm volatile("s_waitcnt vmcnt(0)" ::: "memory");
      __builtin_amdgcn_s_barrier();
    }
  }
#undef GSN

#pragma unroll
  for (int mi = 0; mi < 2; ++mi) {
    const int row = m0 + wm * 64 + mi * 32 + l5;
    const f32x16& ac = (mi == 0) ? acc0 : acc1;
#pragma unroll
    for (int rg = 0; rg < 4; ++rg) {
      const int cb = n0 + wn * 32 + rg * 8 + hi * 4;
      float4 bb4 = *(const float4*)(bias + cb);
      float4 rr = *(const float4*)(res + (size_t)row * N + cb);
      *(float4*)((float*)outp + (size_t)row * N + cb) =
          make_float4(ac[rg * 4 + 0] + bb4.x + rr.x, ac[rg * 4 + 1] + bb4.y + rr.y,
                      ac[rg * 4 + 2] + bb4.z + rr.z, ac[rg * 4 + 3] + bb4.w + rr.w);
    }
  }
}

// ---------------------------------------------------------------------------
// GEMM_W: 128x128 block, 4 waves (2x2), 64x64 per wave (4x f32x16 acc),
// BK=32, 3-buffer counted-vmcnt pipeline, setprio around compute.
// EPI 2: +bias,gelu->bf16   EPI 3: qkv split-write q2/k2/v2 via LDS transpose
// ---------------------------------------------------------------------------
template <int EPI>
__global__ __launch_bounds__(256, 3) void gemm_w(const bf16* __restrict__ A,
                                                 const bf16* __restrict__ Bt,
                                                 const float* __restrict__ bias,
                                                 void* __restrict__ outp,
                                                 bf16* __restrict__ k2,
                                                 bf16* __restrict__ v2,
                                                 int M, int N, int K) {
  __shared__ __align__(16) char smem[49152];
  char* a_lds = smem;           // [3][8192]
  char* b_lds = smem + 24576;   // [3][8192]
  const int tid = threadIdx.x, l = tid & 63, w = tid >> 6;
  const int wm = w >> 1, wn = w & 1;
  const int hi = l >> 5, l5 = l & 31;
  const int m0 = blockIdx.x * 128, n0 = blockIdx.y * 128;
  const int swl = l5 & 7;

  const int sr = tid >> 3, sp = tid & 7;
  const int slc = sp ^ (sr & 7);
  const int shalf = slc >> 2, skc = slc & 3;
  const bf16* ag = A + (size_t)(m0 + shalf * 64 + sr) * K + skc * 8;
  const bf16* bg = Bt + (size_t)(n0 + shalf * 64 + sr) * K + skc * 8;
  const size_t r32 = (size_t)32 * K;

#define GSW(B_)                                                       \
  do {                                                                \
    gload_lds16(ag,       a_lds + (B_) * 8192 + w * 1024);            \
    gload_lds16(ag + r32, a_lds + (B_) * 8192 + 4096 + w * 1024);     \
    gload_lds16(bg,       b_lds + (B_) * 8192 + w * 1024);            \
    gload_lds16(bg + r32, b_lds + (B_) * 8192 + 4096 + w * 1024);     \
    ag += 32; bg += 32;                                               \
  } while (0)

  f32x16 acc00 = {}, acc01 = {}, acc10 = {}, acc11 = {};
  const int kiters = K >> 5;
  GSW(0);
  GSW(1);
  asm volatile("s_waitcnt vmcnt(4)" ::: "memory");
  __builtin_amdgcn_s_barrier();
  for (int kt = 0; kt < kiters; ++kt) {
    if (kt + 2 < kiters) GSW((kt + 2) % 3);
    const char* ab = a_lds + (kt % 3) * 8192;
    const char* bb = b_lds + (kt % 3) * 8192;
    __builtin_amdgcn_s_setprio(1);
#pragma unroll
    for (int kk = 0; kk < 2; ++kk) {
      bf16x8 af0 = *(const bf16x8*)(ab + (l5)*128      + ((wm * 4 + kk * 2 + hi) ^ swl) * 16);
      bf16x8 af1 = *(const bf16x8*)(ab + (32 + l5)*128 + ((wm * 4 + kk * 2 + hi) ^ swl) * 16);
      bf16x8 bf0 = *(const bf16x8*)(bb + (l5)*128      + ((wn * 4 + kk * 2 + hi) ^ swl) * 16);
      bf16x8 bf1 = *(const bf16x8*)(bb + (32 + l5)*128 + ((wn * 4 + kk * 2 + hi) ^ swl) * 16);
      acc00 = MFMA32(bf0, af0, acc00);
      acc01 = MFMA32(bf1, af0, acc01);
      acc10 = MFMA32(bf0, af1, acc10);
      acc11 = MFMA32(bf1, af1, acc11);
    }
    __builtin_amdgcn_s_setprio(0);
    if (kt + 1 < kiters) {
      if (kt + 2 < kiters) asm volatile("s_waitcnt vmcnt(4)" ::: "memory");
      else                 asm volatile("s_waitcnt vmcnt(0)" ::: "memory");
      __builtin_amdgcn_s_barrier();
    }
  }
#undef GSW

  if constexpr (EPI == 2) {  // gelu -> bf16, direct stores
#pragma unroll
    for (int mi = 0; mi < 2; ++mi) {
      const int row = m0 + wm * 64 + mi * 32 + l5;
#pragma unroll
      for (int ni = 0; ni < 2; ++ni) {
        const f32x16& ac = (mi == 0) ? (ni == 0 ? acc00 : acc01)
                                     : (ni == 0 ? acc10 : acc11);
#pragma unroll
        for (int rg = 0; rg < 4; ++rg) {
          const int cb = n0 + wn * 64 + ni * 32 + rg * 8 + hi * 4;
          float4 bb4 = *(const float4*)(bias + cb);
          float v[4] = {ac[rg * 4 + 0] + bb4.x, ac[rg * 4 + 1] + bb4.y,
                        ac[rg * 4 + 2] + bb4.z, ac[rg * 4 + 3] + bb4.w};
          bf16x4 o;
#pragma unroll
          for (int e = 0; e < 4; ++e) {
            float t = -2.3022077697f * (v[e] + 0.044715f * v[e] * v[e] * v[e]);
            o[e] = (bf16)(v[e] / (1.f + fast_exp2(t)));
          }
          *(bf16x4*)((bf16*)outp + (size_t)row * N + cb) = o;
        }
      }
    }
  } else {  // EPI 3: C tile -> LDS (padded) -> coalesced q2/k2/v2
    __syncthreads();
    bf16(*ct)[136] = (bf16(*)[136])smem;   // 128 x 136 bf16
#pragma unroll
    for (int mi = 0; mi < 2; ++mi) {
      const int rl = wm * 64 + mi * 32 + l5;
#pragma unroll
      for (int ni = 0; ni < 2; ++ni) {
        const f32x16& ac = (mi == 0) ? (ni == 0 ? acc00 : acc01)
                                     : (ni == 0 ? acc10 : acc11);
#pragma unroll
        for (int rg = 0; rg < 4; ++rg) {
          const int cl = wn * 64 + ni * 32 + rg * 8 + hi * 4;
          float4 bb4 = *(const float4*)(bias + n0 + cl);
          bf16x4 o;
          o[0] = (bf16)(ac[rg * 4 + 0] + bb4.x);
          o[1] = (bf16)(ac[rg * 4 + 1] + bb4.y);
          o[2] = (bf16)(ac[rg * 4 + 2] + bb4.z);
          o[3] = (bf16)(ac[rg * 4 + 3] + bb4.w);
          *(bf16x4*)(&ct[rl][cl]) = o;
        }
      }
    }
    __syncthreads();
    if (n0 < 512) {            // q2 [t][512]
#pragma unroll
      for (int p = 0; p < 8; ++p) {
        int v = p * 256 + tid;
        int r = v >> 4, c8 = (v & 15) * 8;
        *(bf16x8*)((bf16*)outp + (size_t)(m0 + r) * 512 + n0 + c8) =
            *(const bf16x8*)(&ct[r][c8]);
      }
    } else if (n0 < 1024) {    // k2 [h][t][64], 2 heads per 128-col tile
      const int hb = (n0 - 512) >> 6;
#pragma unroll
      for (int p = 0; p < 8; ++p) {
        int v = p * 256 + tid;
        int r = v >> 4, c8 = (v & 15) * 8;
        *(bf16x8*)(k2 + (size_t)(hb + (c8 >> 6)) * 262144 +
                   (size_t)(m0 + r) * 64 + (c8 & 63)) = *(const bf16x8*)(&ct[r][c8]);
      }
    } else {                   // v2 [h][panel][d][32], 2 heads, 4 panels
      const int hb = (n0 - 1024) >> 6;
      const int d = tid >> 2, t8 = (tid & 3) * 8;
#pragma unroll
      for (int h2 = 0; h2 < 2; ++h2) {
        bf16* vb = v2 + (size_t)(hb + h2) * 262144 + (size_t)(m0 >> 5) * 2048;
#pragma unroll
        for (int p = 0; p < 4; ++p) {
          bf16x8 vv;
#pragma unroll
          for (int e = 0; e < 8; ++e) vv[e] = ct[p * 32 + t8 + e][h2 * 64 + d];
          *(bf16x8*)(vb + p * 2048 + d * 32 + t8) = vv;
        }
      }
    }
  }
}

// ---------------------------------------------------------------------------
// Flash attention v8.1: frozen structure + split staging (K loads issued
// before QK^T, V loads between QK^T and softmax/PV -> K prefetch covered by
// full compute phase, smaller issue bursts). 8 waves/block, grid 512.
// ---------------------------------------------------------------------------
__global__ __launch_bounds__(512, 4) void attn_k(const bf16* __restrict__ q2,
                                                 const bf16* __restrict__ k2,
                                                 const bf16* __restrict__ v2,
                                                 bf16* __restrict__ attnb) {
  const int bid = blockIdx.x;
  const int head = bid & 7;          // one head per XCD (L2 locality)
  const int qt = bid >> 3;
  const int w = threadIdx.x >> 6, l = threadIdx.x & 63;
  const int hi = l >> 5, l5 = l & 31;
  const int pair = w >> 1, wq = w & 1;

  __shared__ __align__(16) char smem[65536];
  char* kt_l = smem + pair * 16384;   // [2][4096] B
  char* vt_l = kt_l + 8192;           // [2][4096] B

  const int qrow0 = qt * 64 + wq * 32;
  const bf16* qb = q2 + (size_t)(qrow0 + l5) * 512 + head * 64;
  bf16x8 qf[4];
#pragma unroll
  for (int cc = 0; cc < 4; ++cc) qf[cc] = *(const bf16x8*)(qb + cc * 16 + hi * 8);

  const int kstart = pair * 1024;

  const int lr = l >> 3;
  const int lc3 = (l & 7) ^ lr;
  const char* kg = (const char*)k2 + (size_t)head * 524288 + (size_t)kstart * 128 +
                   (wq * 16 + lr) * 128 + lc3 * 16;
  const char* vg = (const char*)v2 + (size_t)head * 524288 + (size_t)(kstart >> 5) * 4096 +
                   (lc3 >> 2) * 2048 + (wq * 16 + lr) * 64 + (lc3 & 3) * 16;
  const int kdst = wq * 2048;

#define STAGE_K(B_)                                                          \
  do {                                                                       \
    gload_lds16(kg,        kt_l + (B_) * 4096 + kdst);                       \
    gload_lds16(kg + 1024, kt_l + (B_) * 4096 + kdst + 1024);                \
    kg += 4096;                                                              \
  } while (0)
#define STAGE_V(B_)                                                          \
  do {                                                                       \
    gload_lds16(vg,        vt_l + (B_) * 4096 + kdst);                       \
    gload_lds16(vg + 512,  vt_l + (B_) * 4096 + kdst + 1024);                \
    vg += 4096;                                                              \
  } while (0)

  STAGE_K(0);
  STAGE_V(0);
  __syncthreads();

  f32x16 o0 = {}, o1 = {};
  float psum = 0.f;
  const int swl = l5 & 7;
  const char* kbase = kt_l + l5 * 128;
  const char* vbase = vt_l + l5 * 128;

#pragma unroll 2
  for (int t = 0; t < 32; ++t) {
    const int cur = t & 1;
    if (t < 31) STAGE_K(cur ^ 1);

    __builtin_amdgcn_s_setprio(1);
    f32x16 s = {};
#pragma unroll
    for (int cc = 0; cc < 4; ++cc) {
      bf16x8 kf = *(const bf16x8*)(kbase + cur * 4096 + ((cc * 2 + hi) ^ swl) * 16);
      s = MFMA32(kf, qf[cc], s);
    }
    __builtin_amdgcn_s_setprio(0);

    if (t < 31) STAGE_V(cur ^ 1);

#pragma unroll
    for (int c = 0; c < 2; ++c) {
      float p[8];
#pragma unroll
      for (int j = 0; j < 8; ++j) p[j] = fast_exp2(s[c * 8 + j]);
      psum += ((p[0] + p[1]) + (p[2] + p[3])) + ((p[4] + p[5]) + (p[6] + p[7]));
      unsigned X = pk2(p[0], p[1]), X2 = pk2(p[2], p[3]);
      unsigned Y = pk2(p[4], p[5]), Y2 = pk2(p[6], p[7]);
      asm volatile("v_permlane32_swap_b32 %0, %1" : "+v"(X), "+v"(Y));
      asm volatile("v_permlane32_swap_b32 %0, %1" : "+v"(X2), "+v"(Y2));
      union { unsigned wd[4]; bf16x8 v; } pa;
      pa.wd[0] = X; pa.wd[1] = X2; pa.wd[2] = Y; pa.wd[3] = Y2;
      bf16x8 vf0 = *(const bf16x8*)(vbase + cur * 4096 + ((c * 2 + hi) ^ swl) * 16);
      bf16x8 vf1 = *(const bf16x8*)(vbase + cur * 4096 + ((4 + c * 2 + hi) ^ swl) * 16);
      __builtin_amdgcn_s_setprio(1);
      o0 = MFMA32(vf0, pa.v, o0);
      o1 = MFMA32(vf1, pa.v, o1);
      __builtin_amdgcn_s_setprio(0);
    }
    __syncthreads();
  }
#undef STAGE_K
#undef STAGE_V

  // 4-way key-range combine via LDS (tiles dead). 6 slots x 64 x 33 f32.
  float* comb = (float*)smem;
  if (pair > 0) {
    float* cb = comb + (((pair - 1) * 2 + wq) * 64 + l) * 33;
#pragma unroll
    for (int r = 0; r < 16; ++r) { cb[r] = o0[r]; cb[16 + r] = o1[r]; }
    cb[32] = psum;
  }
  __syncthreads();
  if (pair == 0) {
#pragma unroll
    for (int p = 0; p < 3; ++p) {
      const float* cb = comb + ((p * 2 + wq) * 64 + l) * 33;
#pragma unroll
      for (int r = 0; r < 16; ++r) { o0[r] += cb[r]; o1[r] += cb[16 + r]; }
      psum += cb[32];
    }
    const float lsum = psum + __shfl_xor(psum, 32);
    const float inv = 1.f / lsum;
    bf16* ob = attnb + (size_t)(qrow0 + l5) * 512 + head * 64;
#pragma unroll
    for (int dt = 0; dt < 2; ++dt)
#pragma unroll
      for (int rg = 0; rg < 4; ++rg) {
        bf16x4 vv;
#pragma unroll
        for (int e = 0; e < 4; ++e) {
          const float ov = (dt == 0) ? o0[rg * 4 + e] : o1[rg * 4 + e];
          vv[e] = (bf16)(ov * inv);
        }
        *(bf16x4*)(ob + dt * 32 + rg * 8 + hi * 4) = vv;
      }
  }
}

// ---------------------------------------------------------------------------
extern "C" void kernel_launch(void* const* d_in, const int* in_sizes, int n_in,
                              void* d_out, int out_size, void* d_ws, size_t ws_size,
                              hipStream_t stream) {
  const float* x    = (const float*)d_in[0];
  const float* ln1s = (const float*)d_in[1];
  const float* ln1b = (const float*)d_in[2];
  const float* Wq   = (const float*)d_in[3];
  const float* bq   = (const float*)d_in[4];
  const float* Wk   = (const float*)d_in[5];
  const float* bk   = (const float*)d_in[6];
  const float* Wv   = (const float*)d_in[7];
  const float* bv   = (const float*)d_in[8];
  const float* Wo   = (const float*)d_in[9];
  const float* bo   = (const float*)d_in[10];
  const float* ln2s = (const float*)d_in[11];
  const float* ln2b = (const float*)d_in[12];
  const float* W1   = (const float*)d_in[13];
  const float* b1   = (const float*)d_in[14];
  const float* W2   = (const float*)d_in[15];
  const float* b2   = (const float*)d_in[16];
  float* out = (float*)d_out;

  char* ws = (char*)d_ws;
  bf16*  wqkvT = (bf16*)(ws + 0);          // [1536][512] 1.5M
  bf16*  woT   = (bf16*)(ws + 1572864);    // [512][512]  0.5M
  bf16*  w1T   = (bf16*)(ws + 2097152);    // [2048][512] 2M
  bf16*  w2T   = (bf16*)(ws + 4194304);    // [512][2048] 2M
  float* bqkv  = (float*)(ws + 6291456);   // -> 6297600
  float* x2    = (float*)(ws + 6297600);   // [4096][512] f32 8M -> 14686208
  bf16*  h     = (bf16*)(ws + 14686208);   // 4M -> 18880512 (h / attnb / h2)
  bf16*  q2    = (bf16*)(ws + 18880512);   // 4M -> 23074816
  bf16*  k2    = (bf16*)(ws + 23074816);   // 4M -> 27269120
  bf16*  v2    = (bf16*)(ws + 27269120);   // 4M -> 31463424
  bf16*  attnb = h;
  bf16*  h2    = h;
  bf16*  gbuf  = (bf16*)(ws + 18880512);   // ffn1 out 16M over dead q2/k2/v2

  prep_ln<<<1798, 256, 0, stream>>>(Wq, Wk, Wv, Wo, W1, W2, bq, bk, bv,
                                    wqkvT, woT, w1T, w2T, bqkv, x, ln1s, ln1b, h);
  gemm_w<3><<<dim3(32, 12), 256, 0, stream>>>(h, wqkvT, bqkv, q2, k2, v2,
                                              4096, 1536, 512);
  attn_k<<<512, 512, 0, stream>>>(q2, k2, v2, attnb);
  // wo projection: x2 = attnb @ Wo^T + bo + x
  gemm_n64<1><<<dim3(32, 8), 256, 0, stream>>>(attnb, woT, bo, x, x2, 4096, 512, 512);
  ln_k<<<1024, 256, 0, stream>>>(x2, ln2s, ln2b, h2);
  gemm_w<2><<<dim3(32, 16), 256, 0, stream>>>(h2, w1T, b1, gbuf, nullptr, nullptr,
                                              4096, 2048, 512);
  // ffn2: out = gbuf @ W2^T + b2 + x2
  gemm_n64<1><<<dim3(32, 8), 256, 0, stream>>>(gbuf, w2T, b2, x2, out, 4096, 512, 2048);
}